// Round 5
// baseline (1197.325 us; speedup 1.0000x reference)
//
#include <hip/hip_runtime.h>
#include <hip/hip_bf16.h>
#include <hip/hip_cooperative_groups.h>
#include <math.h>

namespace cg = cooperative_groups;

// N=50000, E=800000, D_IN=64, D_HID=128, D_OUT=64
// R18 = R17 + single cooperative mega-kernel (5 phases, 4 grid.sync) to
// remove all inter-dispatch gaps, + perm-prefill eliminated (cndmask of
// OOB slots to sentinel N in the gather instead of pre-filling 6.4MB).
// 2048 blocks x 256 thr, __launch_bounds__(256,8) -> 64 VGPR cap so all
// phases keep 32 waves/CU. Fallback: 5 plain dispatches if coop launch
// fails (capture-unsupported / occupancy).

typedef unsigned short u16;
typedef unsigned int   u32;
typedef __attribute__((ext_vector_type(8))) __bf16 bf16x8;
typedef __attribute__((ext_vector_type(4))) float  f32x4;

__device__ __forceinline__ u16 f2bf(float f) {            // RNE fp32->bf16
    u32 u = __float_as_uint(f);
    u32 r = (u + 0x7FFFu + ((u >> 16) & 1u)) >> 16;
    return (u16)r;
}
__device__ __forceinline__ float bfl(u32 u) { return __uint_as_float(u << 16); }
__device__ __forceinline__ float bfh(u32 u) { return __uint_as_float(u & 0xFFFF0000u); }
__device__ __forceinline__ u32 pack2(float a, float b) {
    return (u32)f2bf(a) | ((u32)f2bf(b) << 16);
}
__device__ __forceinline__ int pad16(int x) { return (x + 15) & ~15; }

#define MEGA_NBLK 2048
#define MEGA_NTHR 256

struct MegaParams {
    const float* x; const int* src; const int* dst;
    const float* Wl1; const float* bl1; const float* Wr1;
    const float* Wl2; const float* bl2; const float* Wr2;
    int* cnt; u16* perm; u16* xb; u16* aggb; u16* m2b;
    u16* W1c; u16* W2c; float* out;
    int N, E, chunks8, N8, nCvt8, nCnt4;
    float invN8;
};

// ---------------------------------------------------------------------------
// Shared phase bodies (used by mega-kernel and by the fallback dispatches).

// CSR fill body for one virtual block vb (8 node-buckets).
__device__ __forceinline__ void fill_body(
    const int* __restrict__ src, const int* __restrict__ dst,
    int* __restrict__ cnt, u16* __restrict__ perm, int E, int N8,
    float invN8, int vb, int tid)
{
    int g = vb & 7;
    int e0 = (vb >> 3) * 2048 + tid * 8;
    int d[8];
    if (e0 + 8 <= E) {
        int4 d0 = *(const int4*)(dst + e0);
        int4 d1 = *(const int4*)(dst + e0 + 4);
        d[0] = d0.x; d[1] = d0.y; d[2] = d0.z; d[3] = d0.w;
        d[4] = d1.x; d[5] = d1.y; d[6] = d1.z; d[7] = d1.w;
    } else {
        for (int k = 0; k < 8; k++) d[k] = (e0 + k < E) ? dst[e0 + k] : -1;
    }
#pragma unroll
    for (int k = 0; k < 8; k++) {
        int dd = d[k];
        if (dd < 0) continue;
        int b = (int)((float)dd * invN8);
        if (dd >= (b + 1) * N8) b++;
        else if (dd < b * N8) b--;
        if (b != g) continue;
        int pos = atomicAdd(&cnt[dd], 1);
        if (pos < 64) perm[(size_t)dd * 64 + pos] = (u16)src[e0 + k];
    }
}

// Wide branchless gather core: one wave, one node, one 64-slot perm block.
// Slots >= degc are masked to sentinel row N (all-zero) via cndmask -- no
// perm pre-fill needed. 8 lanes/row (16B uint4), paired 2-deep unroll.
// Returns acc[0..7] = cols c8*8..c8*8+7, replicated across row-groups.
__device__ __forceinline__ void gather_wide(
    const u32* __restrict__ feat2, const u16* __restrict__ perm,
    int slot0, int degc, int pd, int rg, int c8, int lane, int N,
    float acc[8])
{
    float accB[8];
#pragma unroll
    for (int k = 0; k < 8; k++) { acc[k] = 0.f; accB[k] = 0.f; }
    int pidx = (int)perm[slot0 + lane];
    pidx = (lane < degc) ? pidx : N;          // OOB slots -> zero row
    for (int j = 0; j < pd; j += 16) {
        int rA = __shfl(pidx, j + rg,     64);
        int rB = __shfl(pidx, j + 8 + rg, 64);
        uint4 uA = *(const uint4*)(feat2 + (size_t)rA * 32 + c8 * 4);
        uint4 uB = *(const uint4*)(feat2 + (size_t)rB * 32 + c8 * 4);
        acc[0] += bfl(uA.x); acc[1] += bfh(uA.x);
        acc[2] += bfl(uA.y); acc[3] += bfh(uA.y);
        acc[4] += bfl(uA.z); acc[5] += bfh(uA.z);
        acc[6] += bfl(uA.w); acc[7] += bfh(uA.w);
        accB[0] += bfl(uB.x); accB[1] += bfh(uB.x);
        accB[2] += bfl(uB.y); accB[3] += bfh(uB.y);
        accB[4] += bfl(uB.z); accB[5] += bfh(uB.z);
        accB[6] += bfl(uB.w); accB[7] += bfh(uB.w);
    }
#pragma unroll
    for (int k = 0; k < 8; k++) acc[k] += accB[k];
#pragma unroll
    for (int k = 0; k < 8; k++) {
        acc[k] += __shfl_xor(acc[k], 8, 64);
        acc[k] += __shfl_xor(acc[k], 16, 64);
        acc[k] += __shfl_xor(acc[k], 32, 64);
    }
}

// gather1 body for one node wid.
__device__ __forceinline__ void gather1_body(
    const u32* __restrict__ xb2, const u16* __restrict__ perm,
    const int* __restrict__ cnt, u32* __restrict__ aggb2, int N,
    int wid, int lane)
{
    int deg = cnt[wid];
    int degc = min(deg, 64);
    int pd = pad16(degc);
    int rg = lane >> 3, c8 = lane & 7;
    float acc[8];
    gather_wide(xb2, perm, wid * 64, degc, pd, rg, c8, lane, N, acc);
    if (rg == 0) {
        float inv = 1.f / fmaxf((float)deg, 1.f);
        uint4 p;
        p.x = pack2(acc[0] * inv, acc[1] * inv);
        p.y = pack2(acc[2] * inv, acc[3] * inv);
        p.z = pack2(acc[4] * inv, acc[5] * inv);
        p.w = pack2(acc[6] * inv, acc[7] * inv);
        *(uint4*)(aggb2 + (size_t)wid * 32 + c8 * 4) = p;
    }
}

// layer12 body for one 64-node tile tb. tileb = this block's 4x2048 u16 LDS.
__device__ __forceinline__ void layer12_body(
    const u16* __restrict__ xb, const u16* __restrict__ aggb,
    const u16* __restrict__ W1, const float* __restrict__ b1,
    const u16* __restrict__ W2, const float* __restrict__ b2,
    u16* __restrict__ m2b, float* __restrict__ out, int N,
    int tb, int tid, u16* tileb)
{
    int wv = tid >> 6, lane = tid & 63;
    int quad = lane >> 4, l16 = lane & 15;
    u16* tile = tileb + wv * 2048;
    int node = tb * 64 + wv * 16 + l16;
    int nclamp = min(node, N - 1);
    const u16* xrow = xb   + (size_t)nclamp * 64;
    const u16* arow = aggb + (size_t)nclamp * 64;
    bf16x8 a0 = *(const bf16x8*)(xrow + quad * 8);
    bf16x8 a1 = *(const bf16x8*)(xrow + 32 + quad * 8);
    bf16x8 a2 = *(const bf16x8*)(arow + quad * 8);
    bf16x8 a3 = *(const bf16x8*)(arow + 32 + quad * 8);
#pragma unroll
    for (int nt = 0; nt < 8; nt++) {
        const u16* wrow = W1 + (size_t)(nt * 16 + l16) * 128 + quad * 8;
        f32x4 acc = {0.f, 0.f, 0.f, 0.f};
        acc = __builtin_amdgcn_mfma_f32_16x16x32_bf16(a0, *(const bf16x8*)(wrow),      acc, 0, 0, 0);
        acc = __builtin_amdgcn_mfma_f32_16x16x32_bf16(a1, *(const bf16x8*)(wrow + 32), acc, 0, 0, 0);
        acc = __builtin_amdgcn_mfma_f32_16x16x32_bf16(a2, *(const bf16x8*)(wrow + 64), acc, 0, 0, 0);
        acc = __builtin_amdgcn_mfma_f32_16x16x32_bf16(a3, *(const bf16x8*)(wrow + 96), acc, 0, 0, 0);
        int col = nt * 16 + l16;
        float bias = b1[col];
#pragma unroll
        for (int r = 0; r < 4; r++) {
            int row = quad * 4 + r;
            tile[row * 128 + (col ^ ((row & 7) << 3))] =
                f2bf(tanhf(acc[r] + bias));
        }
    }
    __syncthreads();
    int swz = (l16 & 7) << 3;
    bf16x8 h0 = *(const bf16x8*)&tile[l16 * 128 + (( 0 + quad * 8) ^ swz)];
    bf16x8 h1 = *(const bf16x8*)&tile[l16 * 128 + ((32 + quad * 8) ^ swz)];
    bf16x8 h2 = *(const bf16x8*)&tile[l16 * 128 + ((64 + quad * 8) ^ swz)];
    bf16x8 h3 = *(const bf16x8*)&tile[l16 * 128 + ((96 + quad * 8) ^ swz)];
    int orow = tb * 64 + wv * 16 + quad * 4;
#pragma unroll
    for (int nt = 0; nt < 8; nt++) {
        const u16* wrow = W2 + (size_t)(nt * 16 + l16) * 128 + quad * 8;
        f32x4 acc = {0.f, 0.f, 0.f, 0.f};
        acc = __builtin_amdgcn_mfma_f32_16x16x32_bf16(h0, *(const bf16x8*)(wrow),      acc, 0, 0, 0);
        acc = __builtin_amdgcn_mfma_f32_16x16x32_bf16(h1, *(const bf16x8*)(wrow + 32), acc, 0, 0, 0);
        acc = __builtin_amdgcn_mfma_f32_16x16x32_bf16(h2, *(const bf16x8*)(wrow + 64), acc, 0, 0, 0);
        acc = __builtin_amdgcn_mfma_f32_16x16x32_bf16(h3, *(const bf16x8*)(wrow + 96), acc, 0, 0, 0);
        int oc = nt * 16 + l16;
#pragma unroll
        for (int r = 0; r < 4; r++) {
            int nn = orow + r;
            if (nn >= N) continue;
            if (oc < 64) m2b[(size_t)nn * 64 + oc] = f2bf(acc[r]);
            else         out[(size_t)nn * 64 + (oc - 64)] = acc[r] + b2[oc - 64];
        }
    }
}

// gather2+final body for one node wid.
__device__ __forceinline__ void gather2_body(
    const u32* __restrict__ m2b2, const u16* __restrict__ perm,
    const int* __restrict__ cnt, float* __restrict__ out, int N,
    int wid, int lane)
{
    int deg = cnt[wid];
    int degc = min(deg, 64);
    int pd = pad16(degc);
    int rg = lane >> 3, c8 = lane & 7;
    float acc[8];
    gather_wide(m2b2, perm, wid * 64, degc, pd, rg, c8, lane, N, acc);
    float inv = 1.f / fmaxf((float)deg, 1.f);
    const float4* orow = (const float4*)(out + (size_t)wid * 64);
    float4 r20 = orow[c8 * 2];
    float4 r21 = orow[c8 * 2 + 1];
    float v[8];
    v[0] = acc[0] * inv + r20.x; v[1] = acc[1] * inv + r20.y;
    v[2] = acc[2] * inv + r20.z; v[3] = acc[3] * inv + r20.w;
    v[4] = acc[4] * inv + r21.x; v[5] = acc[5] * inv + r21.y;
    v[6] = acc[6] * inv + r21.z; v[7] = acc[7] * inv + r21.w;
    float m = v[0];
#pragma unroll
    for (int k = 1; k < 8; k++) m = fmaxf(m, v[k]);
#pragma unroll
    for (int o = 1; o < 8; o <<= 1) m = fmaxf(m, __shfl_xor(m, o, 64));
    float s = 0.f;
#pragma unroll
    for (int k = 0; k < 8; k++) s += expf(v[k] - m);
#pragma unroll
    for (int o = 1; o < 8; o <<= 1) s += __shfl_xor(s, o, 64);
    if (rg == 0) {
        float ls = m + logf(s);
        float4* ow = (float4*)(out + (size_t)wid * 64);
        ow[c8 * 2]     = make_float4(v[0] - ls, v[1] - ls, v[2] - ls, v[3] - ls);
        ow[c8 * 2 + 1] = make_float4(v[4] - ls, v[5] - ls, v[6] - ls, v[7] - ls);
    }
}

// ---------------------------------------------------------------------------
// Cooperative mega-kernel: all 5 phases, grid.sync() between them.
__global__ __launch_bounds__(MEGA_NTHR, 8) void mega_kernel(MegaParams p)
{
    __shared__ u16 tileb[4 * 2048];
    cg::grid_group grid = cg::this_grid();
    const int bid = blockIdx.x, tid = threadIdx.x;
    const int gsz = MEGA_NBLK * MEGA_NTHR;
    const int gtid = bid * MEGA_NTHR + tid;
    const int lane = tid & 63, wv = tid >> 6;

    // ---- Phase A: cvt x->bf16 | weight pack | zero cnt | zero sentinel rows
    for (int i = gtid; i < p.nCvt8; i += gsz) {
        float4 v0 = ((const float4*)p.x)[i * 2];
        float4 v1 = ((const float4*)p.x)[i * 2 + 1];
        uint4 q;
        q.x = pack2(v0.x, v0.y); q.y = pack2(v0.z, v0.w);
        q.z = pack2(v1.x, v1.y); q.w = pack2(v1.z, v1.w);
        ((uint4*)p.xb)[i] = q;
    }
    for (int i = gtid; i < 128 * 128; i += gsz) {
        int o = i >> 7, k = i & 127;
        float w1 = (k < 64) ? p.Wr1[o * 64 + k] : p.Wl1[o * 64 + (k - 64)];
        p.W1c[i] = f2bf(w1);
        float w2 = (o < 64) ? p.Wl2[o * 128 + k] : p.Wr2[(o - 64) * 128 + k];
        p.W2c[i] = f2bf(w2);
    }
    for (int i = gtid; i < p.nCnt4; i += gsz) {
        uint4 z; z.x = 0; z.y = 0; z.z = 0; z.w = 0;
        ((uint4*)p.cnt)[i] = z;
    }
    if (bid == 0) {
        if (tid < 32)      ((u32*)(p.xb  + (size_t)p.N * 64))[tid] = 0;
        else if (tid < 64) ((u32*)(p.m2b + (size_t)p.N * 64))[tid - 32] = 0;
    }
    grid.sync();

    // ---- Phase B: CSR fill (bucketed x8)
    for (int vb = bid; vb < p.chunks8; vb += MEGA_NBLK)
        fill_body(p.src, p.dst, p.cnt, p.perm, p.E, p.N8, p.invN8, vb, tid);
    grid.sync();

    // ---- Phase C: gather1 (aggb = bf16 mean of xb over in-edges)
    for (int wid = bid * 4 + wv; wid < p.N; wid += MEGA_NBLK * 4)
        gather1_body((const u32*)p.xb, p.perm, p.cnt, (u32*)p.aggb, p.N,
                     wid, lane);
    grid.sync();

    // ---- Phase D: fused layer1+layer2
    {
        int ntiles = (p.N + 63) / 64;
        for (int tb = bid; tb < ntiles; tb += MEGA_NBLK) {
            layer12_body(p.xb, p.aggb, p.W1c, p.bl1, p.W2c, p.bl2,
                         p.m2b, p.out, p.N, tb, tid, tileb);
            __syncthreads();
        }
    }
    grid.sync();

    // ---- Phase E: gather2 + log_softmax
    for (int wid = bid * 4 + wv; wid < p.N; wid += MEGA_NBLK * 4)
        gather2_body((const u32*)p.m2b, p.perm, p.cnt, p.out, p.N, wid, lane);
}

// ---------------------------------------------------------------------------
// Fallback plain kernels (R17 structure, prefill removed).
__global__ __launch_bounds__(256) void misc_kernel(
    const float* __restrict__ x, uint4* __restrict__ xb4, int nCvt8,
    const float* __restrict__ Wl1, const float* __restrict__ Wr1,
    const float* __restrict__ Wl2, const float* __restrict__ Wr2,
    u16* __restrict__ W1c, u16* __restrict__ W2c,
    int* __restrict__ cnt, int nCnt4,
    u16* __restrict__ xb, u16* __restrict__ m2b,
    int N, int VB, int ZB)
{
    int blk = blockIdx.x, tid = threadIdx.x;
    if (blk < VB) {
        int i = blk * 256 + tid;
        if (i < nCvt8) {
            float4 v0 = ((const float4*)x)[i * 2];
            float4 v1 = ((const float4*)x)[i * 2 + 1];
            uint4 p;
            p.x = pack2(v0.x, v0.y); p.y = pack2(v0.z, v0.w);
            p.z = pack2(v1.x, v1.y); p.w = pack2(v1.z, v1.w);
            xb4[i] = p;
        }
    } else if (blk < VB + 64) {
        int i = (blk - VB) * 256 + tid;
        if (i < 128 * 128) {
            int o = i >> 7, k = i & 127;
            float w1 = (k < 64) ? Wr1[o * 64 + k] : Wl1[o * 64 + (k - 64)];
            W1c[i] = f2bf(w1);
            float w2 = (o < 64) ? Wl2[o * 128 + k] : Wr2[(o - 64) * 128 + k];
            W2c[i] = f2bf(w2);
        }
    } else if (blk < VB + 64 + ZB) {
        int i = (blk - VB - 64) * 256 + tid;
        if (i < nCnt4) {
            uint4 z; z.x = 0; z.y = 0; z.z = 0; z.w = 0;
            ((uint4*)cnt)[i] = z;
        }
    } else {
        if (tid < 32)      ((u32*)(xb  + (size_t)N * 64))[tid] = 0;
        else if (tid < 64) ((u32*)(m2b + (size_t)N * 64))[tid - 32] = 0;
    }
}

__global__ __launch_bounds__(256) void fill_kernel(
    const int* __restrict__ src, const int* __restrict__ dst,
    int* __restrict__ cnt, u16* __restrict__ perm, int E, int N8, float invN8)
{
    fill_body(src, dst, cnt, perm, E, N8, invN8, blockIdx.x, threadIdx.x);
}

__global__ __launch_bounds__(256) void gather1_kernel(
    const u32* __restrict__ xb2, const u16* __restrict__ perm,
    const int* __restrict__ cnt, u32* __restrict__ aggb2, int N)
{
    int wid = blockIdx.x * 4 + (threadIdx.x >> 6);
    if (wid >= N) return;
    gather1_body(xb2, perm, cnt, aggb2, N, wid, threadIdx.x & 63);
}

__global__ __launch_bounds__(256) void layer12_kernel(
    const u16* __restrict__ xb, const u16* __restrict__ aggb,
    const u16* __restrict__ W1, const float* __restrict__ b1,
    const u16* __restrict__ W2, const float* __restrict__ b2,
    u16* __restrict__ m2b, float* __restrict__ out, int N)
{
    __shared__ u16 tileb[4 * 2048];
    layer12_body(xb, aggb, W1, b1, W2, b2, m2b, out, N,
                 blockIdx.x, threadIdx.x, tileb);
}

__global__ __launch_bounds__(256) void gather2_final_kernel(
    const u32* __restrict__ m2b2, const u16* __restrict__ perm,
    const int* __restrict__ cnt, float* __restrict__ out, int N)
{
    int wid = blockIdx.x * 4 + (threadIdx.x >> 6);
    if (wid >= N) return;
    gather2_body(m2b2, perm, cnt, out, N, wid, threadIdx.x & 63);
}

// ---------------------------------------------------------------------------
extern "C" void kernel_launch(void* const* d_in, const int* in_sizes, int n_in,
                              void* d_out, int out_size, void* d_ws, size_t ws_size,
                              hipStream_t stream)
{
    const float* x   = (const float*)d_in[0];
    const int*   ei  = (const int*)d_in[1];
    const float* Wl1 = (const float*)d_in[2];
    const float* bl1 = (const float*)d_in[3];
    const float* Wr1 = (const float*)d_in[4];
    const float* Wl2 = (const float*)d_in[5];
    const float* bl2 = (const float*)d_in[6];
    const float* Wr2 = (const float*)d_in[7];
    float* out = (float*)d_out;

    int N = in_sizes[0] / 64;   // 50000
    int E = in_sizes[1] / 2;    // 800000
    const int* src = ei;
    const int* dst = ei + E;
    int N8 = (N + 7) / 8;
    float invN8 = 1.0f / (float)N8;
    int chunks = (E + 2047) / 2048;
    int chunks8 = chunks * 8;
    int nCvt8 = N * 64 / 8;
    int nCnt4 = N / 4;

    // Workspace layout (all bases 16B-aligned; ws base 256-aligned).
    char* wsb = (char*)d_ws;
    size_t npad = ((size_t)N + 64) & ~(size_t)63;
    size_t permN = (size_t)N * 64;
    int* cnt  = (int*)wsb;                       // [N] degrees (bump alloc)
    u16* perm = (u16*)(cnt + npad);              // [N*64] u16 (no prefill)
    u16* xb   = perm + permN;                    // [(N+1)*64] bf16 (+zero row)
    u16* aggb = xb + (size_t)(N + 1) * 64;       // [N*64]  bf16
    u16* m2b  = aggb + (size_t)N * 64;           // [(N+1)*64] bf16 (+zero row)
    u16* W1c  = m2b + (size_t)(N + 1) * 64;      // [128*128]
    u16* W2c  = W1c + 128 * 128;                 // [128*128]

    MegaParams p;
    p.x = x; p.src = src; p.dst = dst;
    p.Wl1 = Wl1; p.bl1 = bl1; p.Wr1 = Wr1;
    p.Wl2 = Wl2; p.bl2 = bl2; p.Wr2 = Wr2;
    p.cnt = cnt; p.perm = perm; p.xb = xb; p.aggb = aggb; p.m2b = m2b;
    p.W1c = W1c; p.W2c = W2c; p.out = out;
    p.N = N; p.E = E; p.chunks8 = chunks8; p.N8 = N8;
    p.nCvt8 = nCvt8; p.nCnt4 = nCnt4; p.invN8 = invN8;

    void* args[] = { (void*)&p };
    hipError_t err = hipLaunchCooperativeKernel(
        (const void*)mega_kernel, dim3(MEGA_NBLK), dim3(MEGA_NTHR),
        args, 0, stream);

    if (err != hipSuccess) {
        (void)hipGetLastError();   // clear sticky error, use fallback path
        int VB = (nCvt8 + 255) / 256;
        int ZB = (nCnt4 + 255) / 256;
        misc_kernel<<<VB + 64 + ZB + 1, 256, 0, stream>>>(
            x, (uint4*)xb, nCvt8, Wl1, Wr1, Wl2, Wr2, W1c, W2c,
            cnt, nCnt4, xb, m2b, N, VB, ZB);
        fill_kernel<<<chunks8, 256, 0, stream>>>(src, dst, cnt, perm, E,
                                                 N8, invN8);
        gather1_kernel<<<(N + 3) / 4, 256, 0, stream>>>(
            (const u32*)xb, perm, cnt, (u32*)aggb, N);
        layer12_kernel<<<(N + 63) / 64, 256, 0, stream>>>(
            xb, aggb, W1c, bl1, W2c, bl2, m2b, out, N);
        gather2_final_kernel<<<(N + 3) / 4, 256, 0, stream>>>(
            (const u32*)m2b, perm, cnt, out, N);
    }
}

// Round 6
// 708.365 us; speedup vs baseline: 1.6903x; 1.6903x over previous
//
#include <hip/hip_runtime.h>
#include <hip/hip_bf16.h>
#include <hip/hip_cooperative_groups.h>
#include <math.h>

namespace cg = cooperative_groups;

// N=50000, E=800000, D_IN=64, D_HID=128, D_OUT=64
// R19 = R18 with the VGPR starvation fixed: launch_bounds(256,4) (128-VGPR
// cap, no spills; R18's (256,8) forced 32 VGPRs -> 260MB scratch traffic),
// grid 1024 blocks = 4 blocks/CU exactly co-resident for coop launch.
// Single cooperative mega-kernel, 5 phases, 4 grid.sync; perm-prefill
// eliminated via cndmask-to-sentinel in gather. Fallback: 5 dispatches.

typedef unsigned short u16;
typedef unsigned int   u32;
typedef __attribute__((ext_vector_type(8))) __bf16 bf16x8;
typedef __attribute__((ext_vector_type(4))) float  f32x4;

__device__ __forceinline__ u16 f2bf(float f) {            // RNE fp32->bf16
    u32 u = __float_as_uint(f);
    u32 r = (u + 0x7FFFu + ((u >> 16) & 1u)) >> 16;
    return (u16)r;
}
__device__ __forceinline__ float bfl(u32 u) { return __uint_as_float(u << 16); }
__device__ __forceinline__ float bfh(u32 u) { return __uint_as_float(u & 0xFFFF0000u); }
__device__ __forceinline__ u32 pack2(float a, float b) {
    return (u32)f2bf(a) | ((u32)f2bf(b) << 16);
}
__device__ __forceinline__ int pad16(int x) { return (x + 15) & ~15; }

#define MEGA_NBLK 1024
#define MEGA_NTHR 256

struct MegaParams {
    const float* x; const int* src; const int* dst;
    const float* Wl1; const float* bl1; const float* Wr1;
    const float* Wl2; const float* bl2; const float* Wr2;
    int* cnt; u16* perm; u16* xb; u16* aggb; u16* m2b;
    u16* W1c; u16* W2c; float* out;
    int N, E, chunks8, N8, nCvt8, nCnt4;
    float invN8;
};

// ---------------------------------------------------------------------------
// Shared phase bodies (used by mega-kernel and by the fallback dispatches).

// CSR fill body for one virtual block vb (8 node-buckets).
__device__ __forceinline__ void fill_body(
    const int* __restrict__ src, const int* __restrict__ dst,
    int* __restrict__ cnt, u16* __restrict__ perm, int E, int N8,
    float invN8, int vb, int tid)
{
    int g = vb & 7;
    int e0 = (vb >> 3) * 2048 + tid * 8;
    int d[8];
    if (e0 + 8 <= E) {
        int4 d0 = *(const int4*)(dst + e0);
        int4 d1 = *(const int4*)(dst + e0 + 4);
        d[0] = d0.x; d[1] = d0.y; d[2] = d0.z; d[3] = d0.w;
        d[4] = d1.x; d[5] = d1.y; d[6] = d1.z; d[7] = d1.w;
    } else {
        for (int k = 0; k < 8; k++) d[k] = (e0 + k < E) ? dst[e0 + k] : -1;
    }
#pragma unroll
    for (int k = 0; k < 8; k++) {
        int dd = d[k];
        if (dd < 0) continue;
        int b = (int)((float)dd * invN8);
        if (dd >= (b + 1) * N8) b++;
        else if (dd < b * N8) b--;
        if (b != g) continue;
        int pos = atomicAdd(&cnt[dd], 1);
        if (pos < 64) perm[(size_t)dd * 64 + pos] = (u16)src[e0 + k];
    }
}

// Wide branchless gather core: one wave, one node, one 64-slot perm block.
// Slots >= degc are masked to sentinel row N (all-zero) via cndmask -- no
// perm pre-fill needed. 8 lanes/row (16B uint4), paired 2-deep unroll.
// Returns acc[0..7] = cols c8*8..c8*8+7, replicated across row-groups.
__device__ __forceinline__ void gather_wide(
    const u32* __restrict__ feat2, const u16* __restrict__ perm,
    int slot0, int degc, int pd, int rg, int c8, int lane, int N,
    float acc[8])
{
    float accB[8];
#pragma unroll
    for (int k = 0; k < 8; k++) { acc[k] = 0.f; accB[k] = 0.f; }
    int pidx = (int)perm[slot0 + lane];
    pidx = (lane < degc) ? pidx : N;          // OOB slots -> zero row
    for (int j = 0; j < pd; j += 16) {
        int rA = __shfl(pidx, j + rg,     64);
        int rB = __shfl(pidx, j + 8 + rg, 64);
        uint4 uA = *(const uint4*)(feat2 + (size_t)rA * 32 + c8 * 4);
        uint4 uB = *(const uint4*)(feat2 + (size_t)rB * 32 + c8 * 4);
        acc[0] += bfl(uA.x); acc[1] += bfh(uA.x);
        acc[2] += bfl(uA.y); acc[3] += bfh(uA.y);
        acc[4] += bfl(uA.z); acc[5] += bfh(uA.z);
        acc[6] += bfl(uA.w); acc[7] += bfh(uA.w);
        accB[0] += bfl(uB.x); accB[1] += bfh(uB.x);
        accB[2] += bfl(uB.y); accB[3] += bfh(uB.y);
        accB[4] += bfl(uB.z); accB[5] += bfh(uB.z);
        accB[6] += bfl(uB.w); accB[7] += bfh(uB.w);
    }
#pragma unroll
    for (int k = 0; k < 8; k++) acc[k] += accB[k];
#pragma unroll
    for (int k = 0; k < 8; k++) {
        acc[k] += __shfl_xor(acc[k], 8, 64);
        acc[k] += __shfl_xor(acc[k], 16, 64);
        acc[k] += __shfl_xor(acc[k], 32, 64);
    }
}

// gather1 body for one node wid.
__device__ __forceinline__ void gather1_body(
    const u32* __restrict__ xb2, const u16* __restrict__ perm,
    const int* __restrict__ cnt, u32* __restrict__ aggb2, int N,
    int wid, int lane)
{
    int deg = cnt[wid];
    int degc = min(deg, 64);
    int pd = pad16(degc);
    int rg = lane >> 3, c8 = lane & 7;
    float acc[8];
    gather_wide(xb2, perm, wid * 64, degc, pd, rg, c8, lane, N, acc);
    if (rg == 0) {
        float inv = 1.f / fmaxf((float)deg, 1.f);
        uint4 p;
        p.x = pack2(acc[0] * inv, acc[1] * inv);
        p.y = pack2(acc[2] * inv, acc[3] * inv);
        p.z = pack2(acc[4] * inv, acc[5] * inv);
        p.w = pack2(acc[6] * inv, acc[7] * inv);
        *(uint4*)(aggb2 + (size_t)wid * 32 + c8 * 4) = p;
    }
}

// layer12 body for one 64-node tile tb. tileb = this block's 4x2048 u16 LDS.
__device__ __forceinline__ void layer12_body(
    const u16* __restrict__ xb, const u16* __restrict__ aggb,
    const u16* __restrict__ W1, const float* __restrict__ b1,
    const u16* __restrict__ W2, const float* __restrict__ b2,
    u16* __restrict__ m2b, float* __restrict__ out, int N,
    int tb, int tid, u16* tileb)
{
    int wv = tid >> 6, lane = tid & 63;
    int quad = lane >> 4, l16 = lane & 15;
    u16* tile = tileb + wv * 2048;
    int node = tb * 64 + wv * 16 + l16;
    int nclamp = min(node, N - 1);
    const u16* xrow = xb   + (size_t)nclamp * 64;
    const u16* arow = aggb + (size_t)nclamp * 64;
    bf16x8 a0 = *(const bf16x8*)(xrow + quad * 8);
    bf16x8 a1 = *(const bf16x8*)(xrow + 32 + quad * 8);
    bf16x8 a2 = *(const bf16x8*)(arow + quad * 8);
    bf16x8 a3 = *(const bf16x8*)(arow + 32 + quad * 8);
#pragma unroll
    for (int nt = 0; nt < 8; nt++) {
        const u16* wrow = W1 + (size_t)(nt * 16 + l16) * 128 + quad * 8;
        f32x4 acc = {0.f, 0.f, 0.f, 0.f};
        acc = __builtin_amdgcn_mfma_f32_16x16x32_bf16(a0, *(const bf16x8*)(wrow),      acc, 0, 0, 0);
        acc = __builtin_amdgcn_mfma_f32_16x16x32_bf16(a1, *(const bf16x8*)(wrow + 32), acc, 0, 0, 0);
        acc = __builtin_amdgcn_mfma_f32_16x16x32_bf16(a2, *(const bf16x8*)(wrow + 64), acc, 0, 0, 0);
        acc = __builtin_amdgcn_mfma_f32_16x16x32_bf16(a3, *(const bf16x8*)(wrow + 96), acc, 0, 0, 0);
        int col = nt * 16 + l16;
        float bias = b1[col];
#pragma unroll
        for (int r = 0; r < 4; r++) {
            int row = quad * 4 + r;
            tile[row * 128 + (col ^ ((row & 7) << 3))] =
                f2bf(tanhf(acc[r] + bias));
        }
    }
    __syncthreads();
    int swz = (l16 & 7) << 3;
    bf16x8 h0 = *(const bf16x8*)&tile[l16 * 128 + (( 0 + quad * 8) ^ swz)];
    bf16x8 h1 = *(const bf16x8*)&tile[l16 * 128 + ((32 + quad * 8) ^ swz)];
    bf16x8 h2 = *(const bf16x8*)&tile[l16 * 128 + ((64 + quad * 8) ^ swz)];
    bf16x8 h3 = *(const bf16x8*)&tile[l16 * 128 + ((96 + quad * 8) ^ swz)];
    int orow = tb * 64 + wv * 16 + quad * 4;
#pragma unroll
    for (int nt = 0; nt < 8; nt++) {
        const u16* wrow = W2 + (size_t)(nt * 16 + l16) * 128 + quad * 8;
        f32x4 acc = {0.f, 0.f, 0.f, 0.f};
        acc = __builtin_amdgcn_mfma_f32_16x16x32_bf16(h0, *(const bf16x8*)(wrow),      acc, 0, 0, 0);
        acc = __builtin_amdgcn_mfma_f32_16x16x32_bf16(h1, *(const bf16x8*)(wrow + 32), acc, 0, 0, 0);
        acc = __builtin_amdgcn_mfma_f32_16x16x32_bf16(h2, *(const bf16x8*)(wrow + 64), acc, 0, 0, 0);
        acc = __builtin_amdgcn_mfma_f32_16x16x32_bf16(h3, *(const bf16x8*)(wrow + 96), acc, 0, 0, 0);
        int oc = nt * 16 + l16;
#pragma unroll
        for (int r = 0; r < 4; r++) {
            int nn = orow + r;
            if (nn >= N) continue;
            if (oc < 64) m2b[(size_t)nn * 64 + oc] = f2bf(acc[r]);
            else         out[(size_t)nn * 64 + (oc - 64)] = acc[r] + b2[oc - 64];
        }
    }
}

// gather2+final body for one node wid.
__device__ __forceinline__ void gather2_body(
    const u32* __restrict__ m2b2, const u16* __restrict__ perm,
    const int* __restrict__ cnt, float* __restrict__ out, int N,
    int wid, int lane)
{
    int deg = cnt[wid];
    int degc = min(deg, 64);
    int pd = pad16(degc);
    int rg = lane >> 3, c8 = lane & 7;
    float acc[8];
    gather_wide(m2b2, perm, wid * 64, degc, pd, rg, c8, lane, N, acc);
    float inv = 1.f / fmaxf((float)deg, 1.f);
    const float4* orow = (const float4*)(out + (size_t)wid * 64);
    float4 r20 = orow[c8 * 2];
    float4 r21 = orow[c8 * 2 + 1];
    float v[8];
    v[0] = acc[0] * inv + r20.x; v[1] = acc[1] * inv + r20.y;
    v[2] = acc[2] * inv + r20.z; v[3] = acc[3] * inv + r20.w;
    v[4] = acc[4] * inv + r21.x; v[5] = acc[5] * inv + r21.y;
    v[6] = acc[6] * inv + r21.z; v[7] = acc[7] * inv + r21.w;
    float m = v[0];
#pragma unroll
    for (int k = 1; k < 8; k++) m = fmaxf(m, v[k]);
#pragma unroll
    for (int o = 1; o < 8; o <<= 1) m = fmaxf(m, __shfl_xor(m, o, 64));
    float s = 0.f;
#pragma unroll
    for (int k = 0; k < 8; k++) s += expf(v[k] - m);
#pragma unroll
    for (int o = 1; o < 8; o <<= 1) s += __shfl_xor(s, o, 64);
    if (rg == 0) {
        float ls = m + logf(s);
        float4* ow = (float4*)(out + (size_t)wid * 64);
        ow[c8 * 2]     = make_float4(v[0] - ls, v[1] - ls, v[2] - ls, v[3] - ls);
        ow[c8 * 2 + 1] = make_float4(v[4] - ls, v[5] - ls, v[6] - ls, v[7] - ls);
    }
}

// ---------------------------------------------------------------------------
// Cooperative mega-kernel: all 5 phases, grid.sync() between them.
// launch_bounds(256,4): 128-VGPR cap -> no spills (R18's (256,8)=32 VGPR
// spilled everything); 1024 blocks = 4 blocks/CU co-resident.
__global__ __launch_bounds__(MEGA_NTHR, 4) void mega_kernel(MegaParams p)
{
    __shared__ u16 tileb[4 * 2048];
    cg::grid_group grid = cg::this_grid();
    const int bid = blockIdx.x, tid = threadIdx.x;
    const int gsz = MEGA_NBLK * MEGA_NTHR;
    const int gtid = bid * MEGA_NTHR + tid;
    const int lane = tid & 63, wv = tid >> 6;

    // ---- Phase A: cvt x->bf16 | weight pack | zero cnt | zero sentinel rows
    for (int i = gtid; i < p.nCvt8; i += gsz) {
        float4 v0 = ((const float4*)p.x)[i * 2];
        float4 v1 = ((const float4*)p.x)[i * 2 + 1];
        uint4 q;
        q.x = pack2(v0.x, v0.y); q.y = pack2(v0.z, v0.w);
        q.z = pack2(v1.x, v1.y); q.w = pack2(v1.z, v1.w);
        ((uint4*)p.xb)[i] = q;
    }
    for (int i = gtid; i < 128 * 128; i += gsz) {
        int o = i >> 7, k = i & 127;
        float w1 = (k < 64) ? p.Wr1[o * 64 + k] : p.Wl1[o * 64 + (k - 64)];
        p.W1c[i] = f2bf(w1);
        float w2 = (o < 64) ? p.Wl2[o * 128 + k] : p.Wr2[(o - 64) * 128 + k];
        p.W2c[i] = f2bf(w2);
    }
    for (int i = gtid; i < p.nCnt4; i += gsz) {
        uint4 z; z.x = 0; z.y = 0; z.z = 0; z.w = 0;
        ((uint4*)p.cnt)[i] = z;
    }
    if (bid == 0) {
        if (tid < 32)      ((u32*)(p.xb  + (size_t)p.N * 64))[tid] = 0;
        else if (tid < 64) ((u32*)(p.m2b + (size_t)p.N * 64))[tid - 32] = 0;
    }
    grid.sync();

    // ---- Phase B: CSR fill (bucketed x8)
    for (int vb = bid; vb < p.chunks8; vb += MEGA_NBLK)
        fill_body(p.src, p.dst, p.cnt, p.perm, p.E, p.N8, p.invN8, vb, tid);
    grid.sync();

    // ---- Phase C: gather1 (aggb = bf16 mean of xb over in-edges)
    for (int wid = bid * 4 + wv; wid < p.N; wid += MEGA_NBLK * 4)
        gather1_body((const u32*)p.xb, p.perm, p.cnt, (u32*)p.aggb, p.N,
                     wid, lane);
    grid.sync();

    // ---- Phase D: fused layer1+layer2
    {
        int ntiles = (p.N + 63) / 64;
        for (int tb = bid; tb < ntiles; tb += MEGA_NBLK) {
            layer12_body(p.xb, p.aggb, p.W1c, p.bl1, p.W2c, p.bl2,
                         p.m2b, p.out, p.N, tb, tid, tileb);
            __syncthreads();
        }
    }
    grid.sync();

    // ---- Phase E: gather2 + log_softmax
    for (int wid = bid * 4 + wv; wid < p.N; wid += MEGA_NBLK * 4)
        gather2_body((const u32*)p.m2b, p.perm, p.cnt, p.out, p.N, wid, lane);
}

// ---------------------------------------------------------------------------
// Fallback plain kernels (R17 structure, prefill removed).
__global__ __launch_bounds__(256) void misc_kernel(
    const float* __restrict__ x, uint4* __restrict__ xb4, int nCvt8,
    const float* __restrict__ Wl1, const float* __restrict__ Wr1,
    const float* __restrict__ Wl2, const float* __restrict__ Wr2,
    u16* __restrict__ W1c, u16* __restrict__ W2c,
    int* __restrict__ cnt, int nCnt4,
    u16* __restrict__ xb, u16* __restrict__ m2b,
    int N, int VB, int ZB)
{
    int blk = blockIdx.x, tid = threadIdx.x;
    if (blk < VB) {
        int i = blk * 256 + tid;
        if (i < nCvt8) {
            float4 v0 = ((const float4*)x)[i * 2];
            float4 v1 = ((const float4*)x)[i * 2 + 1];
            uint4 p;
            p.x = pack2(v0.x, v0.y); p.y = pack2(v0.z, v0.w);
            p.z = pack2(v1.x, v1.y); p.w = pack2(v1.z, v1.w);
            xb4[i] = p;
        }
    } else if (blk < VB + 64) {
        int i = (blk - VB) * 256 + tid;
        if (i < 128 * 128) {
            int o = i >> 7, k = i & 127;
            float w1 = (k < 64) ? Wr1[o * 64 + k] : Wl1[o * 64 + (k - 64)];
            W1c[i] = f2bf(w1);
            float w2 = (o < 64) ? Wl2[o * 128 + k] : Wr2[(o - 64) * 128 + k];
            W2c[i] = f2bf(w2);
        }
    } else if (blk < VB + 64 + ZB) {
        int i = (blk - VB - 64) * 256 + tid;
        if (i < nCnt4) {
            uint4 z; z.x = 0; z.y = 0; z.z = 0; z.w = 0;
            ((uint4*)cnt)[i] = z;
        }
    } else {
        if (tid < 32)      ((u32*)(xb  + (size_t)N * 64))[tid] = 0;
        else if (tid < 64) ((u32*)(m2b + (size_t)N * 64))[tid - 32] = 0;
    }
}

__global__ __launch_bounds__(256) void fill_kernel(
    const int* __restrict__ src, const int* __restrict__ dst,
    int* __restrict__ cnt, u16* __restrict__ perm, int E, int N8, float invN8)
{
    fill_body(src, dst, cnt, perm, E, N8, invN8, blockIdx.x, threadIdx.x);
}

__global__ __launch_bounds__(256) void gather1_kernel(
    const u32* __restrict__ xb2, const u16* __restrict__ perm,
    const int* __restrict__ cnt, u32* __restrict__ aggb2, int N)
{
    int wid = blockIdx.x * 4 + (threadIdx.x >> 6);
    if (wid >= N) return;
    gather1_body(xb2, perm, cnt, aggb2, N, wid, threadIdx.x & 63);
}

__global__ __launch_bounds__(256) void layer12_kernel(
    const u16* __restrict__ xb, const u16* __restrict__ aggb,
    const u16* __restrict__ W1, const float* __restrict__ b1,
    const u16* __restrict__ W2, const float* __restrict__ b2,
    u16* __restrict__ m2b, float* __restrict__ out, int N)
{
    __shared__ u16 tileb[4 * 2048];
    layer12_body(xb, aggb, W1, b1, W2, b2, m2b, out, N,
                 blockIdx.x, threadIdx.x, tileb);
}

__global__ __launch_bounds__(256) void gather2_final_kernel(
    const u32* __restrict__ m2b2, const u16* __restrict__ perm,
    const int* __restrict__ cnt, float* __restrict__ out, int N)
{
    int wid = blockIdx.x * 4 + (threadIdx.x >> 6);
    if (wid >= N) return;
    gather2_body(m2b2, perm, cnt, out, N, wid, threadIdx.x & 63);
}

// ---------------------------------------------------------------------------
extern "C" void kernel_launch(void* const* d_in, const int* in_sizes, int n_in,
                              void* d_out, int out_size, void* d_ws, size_t ws_size,
                              hipStream_t stream)
{
    const float* x   = (const float*)d_in[0];
    const int*   ei  = (const int*)d_in[1];
    const float* Wl1 = (const float*)d_in[2];
    const float* bl1 = (const float*)d_in[3];
    const float* Wr1 = (const float*)d_in[4];
    const float* Wl2 = (const float*)d_in[5];
    const float* bl2 = (const float*)d_in[6];
    const float* Wr2 = (const float*)d_in[7];
    float* out = (float*)d_out;

    int N = in_sizes[0] / 64;   // 50000
    int E = in_sizes[1] / 2;    // 800000
    const int* src = ei;
    const int* dst = ei + E;
    int N8 = (N + 7) / 8;
    float invN8 = 1.0f / (float)N8;
    int chunks = (E + 2047) / 2048;
    int chunks8 = chunks * 8;
    int nCvt8 = N * 64 / 8;
    int nCnt4 = N / 4;

    // Workspace layout (all bases 16B-aligned; ws base 256-aligned).
    char* wsb = (char*)d_ws;
    size_t npad = ((size_t)N + 64) & ~(size_t)63;
    size_t permN = (size_t)N * 64;
    int* cnt  = (int*)wsb;                       // [N] degrees (bump alloc)
    u16* perm = (u16*)(cnt + npad);              // [N*64] u16 (no prefill)
    u16* xb   = perm + permN;                    // [(N+1)*64] bf16 (+zero row)
    u16* aggb = xb + (size_t)(N + 1) * 64;       // [N*64]  bf16
    u16* m2b  = aggb + (size_t)N * 64;           // [(N+1)*64] bf16 (+zero row)
    u16* W1c  = m2b + (size_t)(N + 1) * 64;      // [128*128]
    u16* W2c  = W1c + 128 * 128;                 // [128*128]

    MegaParams p;
    p.x = x; p.src = src; p.dst = dst;
    p.Wl1 = Wl1; p.bl1 = bl1; p.Wr1 = Wr1;
    p.Wl2 = Wl2; p.bl2 = bl2; p.Wr2 = Wr2;
    p.cnt = cnt; p.perm = perm; p.xb = xb; p.aggb = aggb; p.m2b = m2b;
    p.W1c = W1c; p.W2c = W2c; p.out = out;
    p.N = N; p.E = E; p.chunks8 = chunks8; p.N8 = N8;
    p.nCvt8 = nCvt8; p.nCnt4 = nCnt4; p.invN8 = invN8;

    void* args[] = { (void*)&p };
    hipError_t err = hipLaunchCooperativeKernel(
        (const void*)mega_kernel, dim3(MEGA_NBLK), dim3(MEGA_NTHR),
        args, 0, stream);

    if (err != hipSuccess) {
        (void)hipGetLastError();   // clear sticky error, use fallback path
        int VB = (nCvt8 + 255) / 256;
        int ZB = (nCnt4 + 255) / 256;
        misc_kernel<<<VB + 64 + ZB + 1, 256, 0, stream>>>(
            x, (uint4*)xb, nCvt8, Wl1, Wr1, Wl2, Wr2, W1c, W2c,
            cnt, nCnt4, xb, m2b, N, VB, ZB);
        fill_kernel<<<chunks8, 256, 0, stream>>>(src, dst, cnt, perm, E,
                                                 N8, invN8);
        gather1_kernel<<<(N + 3) / 4, 256, 0, stream>>>(
            (const u32*)xb, perm, cnt, (u32*)aggb, N);
        layer12_kernel<<<(N + 63) / 64, 256, 0, stream>>>(
            xb, aggb, W1c, bl1, W2c, bl2, m2b, out, N);
        gather2_final_kernel<<<(N + 3) / 4, 256, 0, stream>>>(
            (const u32*)m2b, perm, cnt, out, N);
    }
}

// Round 7
// 197.728 us; speedup vs baseline: 6.0554x; 3.5825x over previous
//
#include <hip/hip_runtime.h>
#include <hip/hip_bf16.h>
#include <math.h>

// N=50000, E=800000, D_IN=64, D_HID=128, D_OUT=64
// R20: coop/grid.sync abandoned (R18/R19: cross-XCD sync forces cold L2 ->
// 623us). Back to plain dispatches, chain shortened to 4:
//   memset(cnt) -> prep(fill|cvt|wpack|zrow, independent virtual blocks)
//   -> gather1+layer12 fused (agg gathered into LDS, swizzled; no aggb
//      round-trip) -> gather2+logsoftmax.
// perm prefill eliminated (cndmask OOB slots to sentinel row N).

typedef unsigned short u16;
typedef unsigned int   u32;
typedef __attribute__((ext_vector_type(8))) __bf16 bf16x8;
typedef __attribute__((ext_vector_type(4))) float  f32x4;

__device__ __forceinline__ u16 f2bf(float f) {            // RNE fp32->bf16
    u32 u = __float_as_uint(f);
    u32 r = (u + 0x7FFFu + ((u >> 16) & 1u)) >> 16;
    return (u16)r;
}
__device__ __forceinline__ float bfl(u32 u) { return __uint_as_float(u << 16); }
__device__ __forceinline__ float bfh(u32 u) { return __uint_as_float(u & 0xFFFF0000u); }
__device__ __forceinline__ u32 pack2(float a, float b) {
    return (u32)f2bf(a) | ((u32)f2bf(b) << 16);
}
__device__ __forceinline__ int pad16(int x) { return (x + 15) & ~15; }

// ---------------------------------------------------------------------------
// CSR fill body for one virtual block vb (8 node-buckets). Fixed-capacity
// rows: slot = dd*64 + atomicAdd(cnt[dd]); cnt ends as true in-degree.
__device__ __forceinline__ void fill_body(
    const int* __restrict__ src, const int* __restrict__ dst,
    int* __restrict__ cnt, u16* __restrict__ perm, int E, int N8,
    float invN8, int vb, int tid)
{
    int g = vb & 7;
    int e0 = (vb >> 3) * 2048 + tid * 8;
    int d[8];
    if (e0 + 8 <= E) {
        int4 d0 = *(const int4*)(dst + e0);
        int4 d1 = *(const int4*)(dst + e0 + 4);
        d[0] = d0.x; d[1] = d0.y; d[2] = d0.z; d[3] = d0.w;
        d[4] = d1.x; d[5] = d1.y; d[6] = d1.z; d[7] = d1.w;
    } else {
        for (int k = 0; k < 8; k++) d[k] = (e0 + k < E) ? dst[e0 + k] : -1;
    }
#pragma unroll
    for (int k = 0; k < 8; k++) {
        int dd = d[k];
        if (dd < 0) continue;
        int b = (int)((float)dd * invN8);
        if (dd >= (b + 1) * N8) b++;
        else if (dd < b * N8) b--;
        if (b != g) continue;
        int pos = atomicAdd(&cnt[dd], 1);
        if (pos < 64) perm[(size_t)dd * 64 + pos] = (u16)src[e0 + k];
    }
}

// ---------------------------------------------------------------------------
// prep: virtual block ranges (all parts independent):
//   [0, FB): CSR fill (needs cnt pre-zeroed by memset)
//   [FB, FB+VB): cvt x->bf16 (8 elems/thread)
//   [FB+VB, +64): weight pack
//   last block: zero sentinel rows xb[N], m2b[N]
__global__ __launch_bounds__(256) void prep_kernel(
    const int* __restrict__ src, const int* __restrict__ dst,
    int* __restrict__ cnt, u16* __restrict__ perm, int E, int N8, float invN8,
    const float* __restrict__ x, uint4* __restrict__ xb4, int nCvt8,
    const float* __restrict__ Wl1, const float* __restrict__ Wr1,
    const float* __restrict__ Wl2, const float* __restrict__ Wr2,
    u16* __restrict__ W1c, u16* __restrict__ W2c,
    u16* __restrict__ xb, u16* __restrict__ m2b,
    int N, int FB, int VB)
{
    int blk = blockIdx.x, tid = threadIdx.x;
    if (blk < FB) {
        fill_body(src, dst, cnt, perm, E, N8, invN8, blk, tid);
    } else if (blk < FB + VB) {
        int i = (blk - FB) * 256 + tid;
        if (i < nCvt8) {
            float4 v0 = ((const float4*)x)[i * 2];
            float4 v1 = ((const float4*)x)[i * 2 + 1];
            uint4 p;
            p.x = pack2(v0.x, v0.y); p.y = pack2(v0.z, v0.w);
            p.z = pack2(v1.x, v1.y); p.w = pack2(v1.z, v1.w);
            xb4[i] = p;
        }
    } else if (blk < FB + VB + 64) {
        int i = (blk - FB - VB) * 256 + tid;
        if (i < 128 * 128) {
            int o = i >> 7, k = i & 127;
            float w1 = (k < 64) ? Wr1[o * 64 + k] : Wl1[o * 64 + (k - 64)];
            W1c[i] = f2bf(w1);
            float w2 = (o < 64) ? Wl2[o * 128 + k] : Wr2[(o - 64) * 128 + k];
            W2c[i] = f2bf(w2);
        }
    } else {
        // zero sentinel rows: xb[N], m2b[N] (64 bf16 = 32 u32 each)
        if (tid < 32)      ((u32*)(xb  + (size_t)N * 64))[tid] = 0;
        else if (tid < 64) ((u32*)(m2b + (size_t)N * 64))[tid - 32] = 0;
    }
}

// ---------------------------------------------------------------------------
// Wide branchless gather core: one wave, one node, one 64-slot perm block.
// Slots >= degc masked to sentinel row N (all-zero) via cndmask -- no perm
// pre-fill needed. 8 lanes/row (16B uint4), paired 2-deep unroll.
// Returns acc[0..7] = cols c8*8..c8*8+7, replicated across row-groups.
__device__ __forceinline__ void gather_wide(
    const u32* __restrict__ feat2, const u16* __restrict__ perm,
    int slot0, int degc, int pd, int rg, int c8, int lane, int N,
    float acc[8])
{
    float accB[8];
#pragma unroll
    for (int k = 0; k < 8; k++) { acc[k] = 0.f; accB[k] = 0.f; }
    int pidx = (int)perm[slot0 + lane];
    pidx = (lane < degc) ? pidx : N;          // OOB slots -> zero row
    for (int j = 0; j < pd; j += 16) {
        int rA = __shfl(pidx, j + rg,     64);
        int rB = __shfl(pidx, j + 8 + rg, 64);
        uint4 uA = *(const uint4*)(feat2 + (size_t)rA * 32 + c8 * 4);
        uint4 uB = *(const uint4*)(feat2 + (size_t)rB * 32 + c8 * 4);
        acc[0] += bfl(uA.x); acc[1] += bfh(uA.x);
        acc[2] += bfl(uA.y); acc[3] += bfh(uA.y);
        acc[4] += bfl(uA.z); acc[5] += bfh(uA.z);
        acc[6] += bfl(uA.w); acc[7] += bfh(uA.w);
        accB[0] += bfl(uB.x); accB[1] += bfh(uB.x);
        accB[2] += bfl(uB.y); accB[3] += bfh(uB.y);
        accB[4] += bfl(uB.z); accB[5] += bfh(uB.z);
        accB[6] += bfl(uB.w); accB[7] += bfh(uB.w);
    }
#pragma unroll
    for (int k = 0; k < 8; k++) acc[k] += accB[k];
#pragma unroll
    for (int k = 0; k < 8; k++) {
        acc[k] += __shfl_xor(acc[k], 8, 64);
        acc[k] += __shfl_xor(acc[k], 16, 64);
        acc[k] += __shfl_xor(acc[k], 32, 64);
    }
}

// ---------------------------------------------------------------------------
// Fused gather1 + layer1 + layer2. Block = 64 nodes, 512 threads (8 waves).
// Phase G: 8 waves x 8 nodes -> agg (bf16 mean of xb over in-edges) into
//          LDS, granule-swizzled (granule g of row r at g^(r&7)) so the
//          MFMA-phase ds_read_b128 is <=2-way bank aliased (free).
// Phase L (waves 0-3): L1 = tanh([xb|agg]@W1^T+b1) -> swizzled LDS tile;
//          L2: tile@[Wl2|Wr2]^T -> m2b (bf16), r2+b2 -> out (fp32).
__global__ __launch_bounds__(512) void gather_layer12_kernel(
    const u16* __restrict__ xb, const u16* __restrict__ perm,
    const int* __restrict__ cnt,
    const u16* __restrict__ W1, const float* __restrict__ b1,
    const u16* __restrict__ W2, const float* __restrict__ b2,
    u16* __restrict__ m2b, float* __restrict__ out, int N)
{
    __shared__ u16 agg_lds[64 * 64];               // 8 KB
    __shared__ u16 tile4[4 * 2048];                // 16 KB
    const int tid = threadIdx.x;
    const int wv = tid >> 6, lane = tid & 63;
    const int tb = blockIdx.x;

    // ---- Phase G: gather agg for this block's 64 nodes
    {
        const int rg = lane >> 3, c8 = lane & 7;
#pragma unroll 2
        for (int i = 0; i < 8; i++) {
            int rr = wv * 8 + i;                   // block row 0..63
            int nodec = min(tb * 64 + rr, N - 1);  // clamp dup (as aggb did)
            int deg = cnt[nodec];
            int degc = min(deg, 64);
            int pd = pad16(degc);
            float acc[8];
            gather_wide((const u32*)xb, perm, nodec * 64, degc, pd,
                        rg, c8, lane, N, acc);
            if (rg == 0) {
                float inv = 1.f / fmaxf((float)deg, 1.f);
                uint4 p;
                p.x = pack2(acc[0] * inv, acc[1] * inv);
                p.y = pack2(acc[2] * inv, acc[3] * inv);
                p.z = pack2(acc[4] * inv, acc[5] * inv);
                p.w = pack2(acc[6] * inv, acc[7] * inv);
                *(uint4*)&agg_lds[rr * 64 + ((c8 ^ (rr & 7)) << 3)] = p;
            }
        }
    }
    __syncthreads();

    // ---- Phase L1 (waves 0-3): 16 nodes per wave
    const int quad = lane >> 4, l16 = lane & 15;
    u16* tile = tile4 + wv * 2048;
    bf16x8 a0, a1, a2, a3;
    if (wv < 4) {
        int node = tb * 64 + wv * 16 + l16;
        int nclamp = min(node, N - 1);
        const u16* xrow = xb + (size_t)nclamp * 64;
        a0 = *(const bf16x8*)(xrow + quad * 8);
        a1 = *(const bf16x8*)(xrow + 32 + quad * 8);
        int rr = wv * 16 + l16;
        a2 = *(const bf16x8*)&agg_lds[rr * 64 + ((quad       ^ (rr & 7)) << 3)];
        a3 = *(const bf16x8*)&agg_lds[rr * 64 + (((quad + 4) ^ (rr & 7)) << 3)];
#pragma unroll
        for (int nt = 0; nt < 8; nt++) {
            const u16* wrow = W1 + (size_t)(nt * 16 + l16) * 128 + quad * 8;
            f32x4 acc = {0.f, 0.f, 0.f, 0.f};
            acc = __builtin_amdgcn_mfma_f32_16x16x32_bf16(a0, *(const bf16x8*)(wrow),      acc, 0, 0, 0);
            acc = __builtin_amdgcn_mfma_f32_16x16x32_bf16(a1, *(const bf16x8*)(wrow + 32), acc, 0, 0, 0);
            acc = __builtin_amdgcn_mfma_f32_16x16x32_bf16(a2, *(const bf16x8*)(wrow + 64), acc, 0, 0, 0);
            acc = __builtin_amdgcn_mfma_f32_16x16x32_bf16(a3, *(const bf16x8*)(wrow + 96), acc, 0, 0, 0);
            int col = nt * 16 + l16;
            float bias = b1[col];
#pragma unroll
            for (int r = 0; r < 4; r++) {
                int row = quad * 4 + r;
                tile[row * 128 + (col ^ ((row & 7) << 3))] =
                    f2bf(tanhf(acc[r] + bias));
            }
        }
    }
    __syncthreads();

    // ---- Phase L2 (waves 0-3)
    if (wv < 4) {
        int swz = (l16 & 7) << 3;
        bf16x8 h0 = *(const bf16x8*)&tile[l16 * 128 + (( 0 + quad * 8) ^ swz)];
        bf16x8 h1 = *(const bf16x8*)&tile[l16 * 128 + ((32 + quad * 8) ^ swz)];
        bf16x8 h2 = *(const bf16x8*)&tile[l16 * 128 + ((64 + quad * 8) ^ swz)];
        bf16x8 h3 = *(const bf16x8*)&tile[l16 * 128 + ((96 + quad * 8) ^ swz)];
        int orow = tb * 64 + wv * 16 + quad * 4;
#pragma unroll
        for (int nt = 0; nt < 8; nt++) {
            const u16* wrow = W2 + (size_t)(nt * 16 + l16) * 128 + quad * 8;
            f32x4 acc = {0.f, 0.f, 0.f, 0.f};
            acc = __builtin_amdgcn_mfma_f32_16x16x32_bf16(h0, *(const bf16x8*)(wrow),      acc, 0, 0, 0);
            acc = __builtin_amdgcn_mfma_f32_16x16x32_bf16(h1, *(const bf16x8*)(wrow + 32), acc, 0, 0, 0);
            acc = __builtin_amdgcn_mfma_f32_16x16x32_bf16(h2, *(const bf16x8*)(wrow + 64), acc, 0, 0, 0);
            acc = __builtin_amdgcn_mfma_f32_16x16x32_bf16(h3, *(const bf16x8*)(wrow + 96), acc, 0, 0, 0);
            int oc = nt * 16 + l16;
#pragma unroll
            for (int r = 0; r < 4; r++) {
                int nn = orow + r;
                if (nn >= N) continue;
                if (oc < 64) m2b[(size_t)nn * 64 + oc] = f2bf(acc[r]);
                else         out[(size_t)nn * 64 + (oc - 64)] = acc[r] + b2[oc - 64];
            }
        }
    }
}

// ---------------------------------------------------------------------------
// gather2+final: out[n] = log_softmax( sum(m2b[perm])/deg + r2[n] ).
// After gather_wide, acc replicated across row-groups -> 3 xor-round reduce.
__global__ __launch_bounds__(256) void gather2_final_kernel(
    const u32* __restrict__ m2b2, const u16* __restrict__ perm,
    const int* __restrict__ cnt, float* __restrict__ out, int N)
{
    int wid  = blockIdx.x * 4 + (threadIdx.x >> 6);
    int lane = threadIdx.x & 63;
    if (wid >= N) return;
    int deg = cnt[wid];
    int degc = min(deg, 64);
    int pd = pad16(degc);
    int rg = lane >> 3, c8 = lane & 7;
    float acc[8];
    gather_wide(m2b2, perm, wid * 64, degc, pd, rg, c8, lane, N, acc);
    float inv = 1.f / fmaxf((float)deg, 1.f);
    const float4* orow = (const float4*)(out + (size_t)wid * 64);
    float4 r20 = orow[c8 * 2];
    float4 r21 = orow[c8 * 2 + 1];
    float v[8];
    v[0] = acc[0] * inv + r20.x; v[1] = acc[1] * inv + r20.y;
    v[2] = acc[2] * inv + r20.z; v[3] = acc[3] * inv + r20.w;
    v[4] = acc[4] * inv + r21.x; v[5] = acc[5] * inv + r21.y;
    v[6] = acc[6] * inv + r21.z; v[7] = acc[7] * inv + r21.w;
    float m = v[0];
#pragma unroll
    for (int k = 1; k < 8; k++) m = fmaxf(m, v[k]);
#pragma unroll
    for (int o = 1; o < 8; o <<= 1) m = fmaxf(m, __shfl_xor(m, o, 64));
    float s = 0.f;
#pragma unroll
    for (int k = 0; k < 8; k++) s += expf(v[k] - m);
#pragma unroll
    for (int o = 1; o < 8; o <<= 1) s += __shfl_xor(s, o, 64);
    if (rg == 0) {
        float ls = m + logf(s);
        float4* ow = (float4*)(out + (size_t)wid * 64);
        ow[c8 * 2]     = make_float4(v[0] - ls, v[1] - ls, v[2] - ls, v[3] - ls);
        ow[c8 * 2 + 1] = make_float4(v[4] - ls, v[5] - ls, v[6] - ls, v[7] - ls);
    }
}

// ---------------------------------------------------------------------------
extern "C" void kernel_launch(void* const* d_in, const int* in_sizes, int n_in,
                              void* d_out, int out_size, void* d_ws, size_t ws_size,
                              hipStream_t stream)
{
    const float* x   = (const float*)d_in[0];
    const int*   ei  = (const int*)d_in[1];
    const float* Wl1 = (const float*)d_in[2];
    const float* bl1 = (const float*)d_in[3];
    const float* Wr1 = (const float*)d_in[4];
    const float* Wl2 = (const float*)d_in[5];
    const float* bl2 = (const float*)d_in[6];
    const float* Wr2 = (const float*)d_in[7];
    float* out = (float*)d_out;

    int N = in_sizes[0] / 64;   // 50000
    int E = in_sizes[1] / 2;    // 800000
    const int* src = ei;
    const int* dst = ei + E;
    int N8 = (N + 7) / 8;
    float invN8 = 1.0f / (float)N8;
    int chunks = (E + 2047) / 2048;
    int FB = chunks * 8;                         // fill virtual blocks
    int nCvt8 = N * 64 / 8;
    int VB = (nCvt8 + 255) / 256;                // cvt virtual blocks

    // Workspace layout (ws base 256-aligned; segments 16B-aligned).
    char* wsb = (char*)d_ws;
    size_t npad = ((size_t)N + 64) & ~(size_t)63;
    size_t permN = (size_t)N * 64;
    int* cnt  = (int*)wsb;                       // [N] degrees
    u16* perm = (u16*)(cnt + npad);              // [N*64] u16 (no prefill)
    u16* xb   = perm + permN;                    // [(N+1)*64] bf16 (+zero row)
    u16* m2b  = xb + (size_t)(N + 1) * 64;       // [(N+1)*64] bf16 (+zero row)
    u16* W1c  = m2b + (size_t)(N + 1) * 64;      // [128*128]
    u16* W2c  = W1c + 128 * 128;                 // [128*128]

    // 1) zero degree counters (graph-capture-legal async memset)
    hipMemsetAsync(cnt, 0, (size_t)N * sizeof(int), stream);

    // 2) prep: fill | cvt | weight pack | sentinel rows (independent parts)
    prep_kernel<<<FB + VB + 64 + 1, 256, 0, stream>>>(
        src, dst, cnt, perm, E, N8, invN8,
        x, (uint4*)xb, nCvt8,
        Wl1, Wr1, Wl2, Wr2, W1c, W2c, xb, m2b, N, FB, VB);

    // 3) fused gather1 + layer1 + layer2
    gather_layer12_kernel<<<(N + 63) / 64, 512, 0, stream>>>(
        xb, perm, cnt, W1c, bl1, W2c, bl2, m2b, out, N);

    // 4) gather2 + log_softmax
    gather2_final_kernel<<<(N + 3) / 4, 256, 0, stream>>>(
        (const u32*)m2b, perm, cnt, out, N);
}